// Round 9
// baseline (173.637 us; speedup 1.0000x reference)
//
#include <hip/hip_runtime.h>

// 10 steps of anisotropic 2D heat stencil, 48x48, B=16384.
// TWO images per wave, 32 lanes each (lane>>5 selects image). Per lane:
// h=lane&31, r=h&7 (8 strips x 6 rows), c=h>>3 (4 strips x 12 cols) ->
// 6x12 patch as 6 rows x 6 v2f in registers (~36 regs state, NOT round 7's
// 72+48: state doubles but halo/coef/shuffle overhead per image halves).
// Vertical halo: DPP row_shr/shl:1 (invalid boundary lanes are exactly the
// r==0 / r==7 lanes, which the frozen-ghost cndmask overwrites anyway).
// Horizontal halo: bpermute lane+-8. Frozen reflect ghosts (initial state):
// row ghost = own v[1] (top) / v[4] (bottom); col ghost = own col 1 / 46.
// waves_per_eu(2,4): 256-reg budget -> no spill (tripwire: WRITE_SIZE).

typedef float v2f __attribute__((ext_vector_type(2)));

constexpr int NXY   = 48;
constexpr int CELLS = NXY * NXY;   // 2304
constexpr int NT    = 10;
constexpr int WPB   = 4;           // waves per block (8 images/block)
constexpr int TPB   = 64 * WPB;

// lane i <- lane i-1 within 16-lane DPP row; invalid lanes -> 0 (cndmask'd)
__device__ __forceinline__ float dpp_shr1(float x) {
    return __int_as_float(__builtin_amdgcn_update_dpp(
        0, __float_as_int(x), 0x111, 0xF, 0xF, true));
}
// lane i <- lane i+1
__device__ __forceinline__ float dpp_shl1(float x) {
    return __int_as_float(__builtin_amdgcn_update_dpp(
        0, __float_as_int(x), 0x101, 0xF, 0xF, true));
}

__global__ __launch_bounds__(TPB)
__attribute__((amdgpu_waves_per_eu(2, 4)))
void pde_heat_kernel(const float* __restrict__ u0,
                     const float* __restrict__ aw,
                     const float* __restrict__ bw,
                     float* __restrict__ out)
{
    const int lane = threadIdx.x & 63;
    const int h    = lane & 31;                       // index within image half
    const int img  = (blockIdx.x * WPB + (threadIdx.x >> 6)) * 2 + (lane >> 5);
    const int r = h & 7;                              // 8 row-strips of 6 rows
    const int c = h >> 3;                             // 4 col-strips of 12 cols

    const float4* __restrict__ u4 = (const float4*)(u0 + (long long)img * CELLS);
    float4*       __restrict__ o4 = (float4*)(out + (long long)img * CELLS);

    // ---- load 6x12 patch: rows r*6.., float4-cols c*3.. (16B aligned) ----
    v2f v[6][6];
    #pragma unroll
    for (int ii = 0; ii < 6; ++ii)
        #pragma unroll
        for (int k = 0; k < 3; ++k) {
            float4 t = u4[(r * 6 + ii) * 12 + c * 3 + k];
            v[ii][2*k]   = (v2f){t.x, t.y};
            v[ii][2*k+1] = (v2f){t.z, t.w};
        }

    // ---- coefficients (v_sin/v_cos take REVOLUTIONS: sin(2pi*x)=v_sin(x)) ----
    // alpha(i) scales axis-0 diff: 0.5*dt/dx^2 = 1.152 ; beta(j): dt/dy^2 = 2.304
    const float a0 = aw[0], a1 = aw[1], a2 = aw[2];
    const float b0 = bw[0], b1 = bw[1], b2 = bw[2];
    float ca[6], cb[12];
    #pragma unroll
    for (int ii = 0; ii < 6; ++ii) {
        float y = (float)(r * 6 + ii) * (1.0f / 47.0f);
        ca[ii] = 1.152f * (a0 + a1 * __builtin_amdgcn_sinf(y)
                              + a2 * __builtin_amdgcn_sinf(2.0f * y));
    }
    #pragma unroll
    for (int jj = 0; jj < 12; ++jj) {
        float x = (float)(c * 12 + jj) * (1.0f / 47.0f);
        cb[jj] = 2.304f * (b0 + b1 * __builtin_amdgcn_cosf(x)
                              + b2 * __builtin_amdgcn_cosf(2.0f * x));
    }

    // ---- frozen reflect ghosts (from INITIAL state) ----
    // top (r==0): u0 row 1  = own v[1];  bottom (r==7): u0 row 46 = 7*6+4 = own v[4]
    // left (c==0): col 1 = v[ii][0].y;   right (c==3): col 46 = local 10 = v[ii][5].x
    v2f gV[6];
    #pragma unroll
    for (int k = 0; k < 6; ++k) gV[k] = (r == 0) ? v[1][k] : v[4][k];
    float gH[6];
    #pragma unroll
    for (int ii = 0; ii < 6; ++ii) gH[ii] = (c == 0) ? v[ii][0].y : v[ii][5].x;

    const int laneL = lane - 8, laneR = lane + 8;
    const bool rTop = (r == 0), rBot = (r == 7), cLft = (c == 0), cRgt = (c == 3);

    // ---- time loop: fully unrolled; DPP vertical + 12 bperm/step horizontal ----
    #pragma unroll
    for (int t = 0; t < NT; ++t) {
        v2f ab[6], hb[6];                 // row above patch / row below patch (old)
        #pragma unroll
        for (int k = 0; k < 6; ++k) {
            float dx0 = dpp_shr1(v[5][k].x), dy0 = dpp_shr1(v[5][k].y);
            ab[k].x = rTop ? gV[k].x : dx0;
            ab[k].y = rTop ? gV[k].y : dy0;
            float ex0 = dpp_shl1(v[0][k].x), ey0 = dpp_shl1(v[0][k].y);
            hb[k].x = rBot ? gV[k].x : ex0;
            hb[k].y = rBot ? gV[k].y : ey0;
        }

        #pragma unroll
        for (int ii = 0; ii < 6; ++ii) {
            float hl = __shfl(v[ii][5].y, laneL);   // left neighbor's col 11
            float hr = __shfl(v[ii][0].x, laneR);   // right neighbor's col 0
            hl = cLft ? gH[ii] : hl;
            hr = cRgt ? gH[ii] : hr;

            v2f nrow[6];
            #pragma unroll
            for (int k = 0; k < 6; ++k) {
                v2f cv    = v[ii][k];
                v2f below = (ii < 5) ? v[ii + 1][k] : hb[k];
                v2f uxx   = (ab[k] + below) - 2.0f * cv;        // packed
                float lf0 = (k > 0) ? v[ii][k - 1].y : hl;
                float rt1 = (k < 5) ? v[ii][k + 1].x : hr;
                float uy0 = (lf0 + cv.y)  - 2.0f * cv.x;        // scalar uyy
                float uy1 = (cv.x + rt1)  - 2.0f * cv.y;
                nrow[k].x = fmaf(cb[2*k],   uy0, fmaf(ca[ii], uxx.x, cv.x));
                nrow[k].y = fmaf(cb[2*k+1], uy1, fmaf(ca[ii], uxx.y, cv.y));
            }
            #pragma unroll
            for (int k = 0; k < 6; ++k) { ab[k] = v[ii][k]; v[ii][k] = nrow[k]; }
        }
    }

    // ---- store ----
    #pragma unroll
    for (int ii = 0; ii < 6; ++ii)
        #pragma unroll
        for (int k = 0; k < 3; ++k) {
            float4 t;
            t.x = v[ii][2*k].x;   t.y = v[ii][2*k].y;
            t.z = v[ii][2*k+1].x; t.w = v[ii][2*k+1].y;
            o4[(r * 6 + ii) * 12 + c * 3 + k] = t;
        }
}

extern "C" void kernel_launch(void* const* d_in, const int* in_sizes, int n_in,
                              void* d_out, int out_size, void* d_ws, size_t ws_size,
                              hipStream_t stream) {
    const float* u0 = (const float*)d_in[0];
    const float* aw = (const float*)d_in[1];
    const float* bw = (const float*)d_in[2];
    float* out = (float*)d_out;

    const int B = in_sizes[0] / CELLS;            // 16384 images
    const int nBlocks = (B / 2) / WPB;            // 8192 waves / 4 per block
    pde_heat_kernel<<<nBlocks, TPB, 0, stream>>>(u0, aw, bw, out);
}

// Round 10
// 83.908 us; speedup vs baseline: 2.0694x; 2.0694x over previous
//
#include <hip/hip_runtime.h>

// 10 steps of anisotropic 2D heat stencil, 48x48, B=16384.
// Wave = image (PROVEN no-spill structure from rounds 6/8: 56 VGPR).
// Lane layout 16x4: (r,c)=(lane&15, lane>>4), patch 3x12 as 6 v2f/row ->
// packed v_pk_add/fma_f32. Vertical halo: DPP row shifts with frozen reflect
// ghost as 'old'. Horizontal halo: 6 bpermutes/step, batched up front.
// Round-10 trims (zero extra state): (a) shared shifted pairs M[0..6]
// (L[k+1]==R[k], halves pair-builds), (b) full t-unroll so row rotations
// become renames and steps overlap. Ghosts = reflect pad of INITIAL state.

typedef float v2f __attribute__((ext_vector_type(2)));

constexpr int NXY   = 48;
constexpr int CELLS = NXY * NXY;     // 2304
constexpr int NT    = 10;
constexpr int WPB   = 4;             // waves (images) per block
constexpr int TPB   = 64 * WPB;

// lane i <- lane i-1 within each 16-lane DPP row; invalid (i%16==0) keeps oldv
__device__ __forceinline__ float dpp_up(float oldv, float src) {
    return __int_as_float(__builtin_amdgcn_update_dpp(
        __float_as_int(oldv), __float_as_int(src), 0x111, 0xF, 0xF, false));
}
// lane i <- lane i+1; invalid (i%16==15) keeps oldv
__device__ __forceinline__ float dpp_dn(float oldv, float src) {
    return __int_as_float(__builtin_amdgcn_update_dpp(
        __float_as_int(oldv), __float_as_int(src), 0x101, 0xF, 0xF, false));
}
__device__ __forceinline__ v2f dpp_up2(v2f o, v2f s) {
    v2f r; r.x = dpp_up(o.x, s.x); r.y = dpp_up(o.y, s.y); return r;
}
__device__ __forceinline__ v2f dpp_dn2(v2f o, v2f s) {
    v2f r; r.x = dpp_dn(o.x, s.x); r.y = dpp_dn(o.y, s.y); return r;
}

__global__ __launch_bounds__(TPB)
__attribute__((amdgpu_waves_per_eu(4, 8)))
void pde_heat_kernel(
    const float* __restrict__ u0,
    const float* __restrict__ aw,
    const float* __restrict__ bw,
    float* __restrict__ out)
{
    const int lane = threadIdx.x & 63;
    const int img  = blockIdx.x * WPB + (threadIdx.x >> 6);
    const int r = lane & 15;         // patch-row strip (16 strips of 3 rows)
    const int c = lane >> 4;         // patch-col strip (4 strips of 12 cols)
    const float4* __restrict__ u4 = (const float4*)(u0 + (long long)img * CELLS);
    float4*       __restrict__ o4 = (float4*)(out + (long long)img * CELLS);

    const int fb = r * 36 + c * 3;   // float4 index of patch (row0, col0)

    // ---- direct load: 9 x global_load_dwordx4 -> 6 x v2f per row ----
    v2f v[3][6];
    #pragma unroll
    for (int ii = 0; ii < 3; ++ii)
        #pragma unroll
        for (int k = 0; k < 3; ++k) {
            float4 t = u4[fb + 12 * ii + k];
            v[ii][2*k]   = (v2f){t.x, t.y};
            v[ii][2*k+1] = (v2f){t.z, t.w};
        }

    // ---- coefficients (v_sin/v_cos take REVOLUTIONS: sin(2pi*x) = v_sin(x)) ----
    // alpha(i) scales axis-0 diff: 0.5*dt/dx^2 = 1.152 ; beta(j): dt/dy^2 = 2.304
    const float a0 = aw[0], a1 = aw[1], a2 = aw[2];
    const float b0 = bw[0], b1 = bw[1], b2 = bw[2];
    float ca[3];
    #pragma unroll
    for (int ii = 0; ii < 3; ++ii) {
        float y = (float)(3 * r + ii) * (1.0f / 47.0f);
        ca[ii] = 1.152f * (a0 + a1 * __builtin_amdgcn_sinf(y)
                              + a2 * __builtin_amdgcn_sinf(2.0f * y));
    }
    v2f cb2[6];
    #pragma unroll
    for (int k = 0; k < 6; ++k) {
        float x0 = (float)(12 * c + 2 * k)     * (1.0f / 47.0f);
        float x1 = (float)(12 * c + 2 * k + 1) * (1.0f / 47.0f);
        cb2[k].x = 2.304f * (b0 + b1 * __builtin_amdgcn_cosf(x0)
                                + b2 * __builtin_amdgcn_cosf(2.0f * x0));
        cb2[k].y = 2.304f * (b0 + b1 * __builtin_amdgcn_cosf(x1)
                                + b2 * __builtin_amdgcn_cosf(2.0f * x1));
    }

    // ---- frozen reflect ghosts (from INITIAL state) ----
    // top (r==0): u0 row 1 = own v[1]; bottom (r==15): row 46 = 3*15+1 = own v[1]
    // left (c==0): col 1 = v[ii][0].y; right (c==3): col 46 = elem 10 = v[ii][5].x
    v2f gV[6];
    #pragma unroll
    for (int k = 0; k < 6; ++k) gV[k] = v[1][k];
    float gH[3];
    #pragma unroll
    for (int ii = 0; ii < 3; ++ii) gH[ii] = (c == 0) ? v[ii][0].y : v[ii][5].x;

    const int laneL = lane - 16, laneR = lane + 16;
    const bool cLft = (c == 0), cRgt = (c == 3);

    // ---- time loop: FULLY UNROLLED; all halos captured up front per step ----
    #pragma unroll
    for (int t = 0; t < NT; ++t) {
        // vertical halos (old values; dpp old-operand = frozen ghost)
        v2f hb[6], ab[6];
        #pragma unroll
        for (int k = 0; k < 6; ++k) hb[k] = dpp_dn2(gV[k], v[0][k]);
        #pragma unroll
        for (int k = 0; k < 6; ++k) ab[k] = dpp_up2(gV[k], v[2][k]);

        // horizontal halos for ALL rows, batched (one lgkmcnt window)
        float hl[3], hr[3];
        #pragma unroll
        for (int ii = 0; ii < 3; ++ii) {
            float l = __shfl(v[ii][5].y, laneL);   // left neighbor's col 11
            float rr = __shfl(v[ii][0].x, laneR);  // right neighbor's col 0
            hl[ii] = cLft ? gH[ii] : l;
            hr[ii] = cRgt ? gH[ii] : rr;
        }

        #pragma unroll
        for (int ii = 0; ii < 3; ++ii) {
            // shared shifted pairs: M[k] = {col 2k-1, col 2k} (old values)
            // L[k] = M[k], R[k] = M[k+1]  (L[k+1] == R[k] dedup)
            v2f M[7];
            M[0] = (v2f){hl[ii], v[ii][0].x};
            #pragma unroll
            for (int k = 1; k < 6; ++k) M[k] = (v2f){v[ii][k-1].y, v[ii][k].x};
            M[6] = (v2f){v[ii][5].y, hr[ii]};

            v2f nrow[6];
            #pragma unroll
            for (int k = 0; k < 6; ++k) {
                v2f cv    = v[ii][k];
                v2f below = (ii < 2) ? v[ii + 1][k] : hb[k];
                v2f s1  = ab[k] + below;
                v2f s2  = M[k] + M[k + 1];
                v2f uxx = s1 - 2.0f * cv;            // pk_fma(-2, cv, s1)
                v2f uyy = s2 - 2.0f * cv;            // pk_fma(-2, cv, s2)
                nrow[k] = cv + ca[ii] * uxx + cb2[k] * uyy;  // 2x pk_fma
            }
            // rotation: renames under full unroll (no movs)
            #pragma unroll
            for (int k = 0; k < 6; ++k) { ab[k] = v[ii][k]; v[ii][k] = nrow[k]; }
        }
    }

    // ---- direct store: 9 x global_store_dwordx4 ----
    #pragma unroll
    for (int ii = 0; ii < 3; ++ii)
        #pragma unroll
        for (int k = 0; k < 3; ++k) {
            float4 t;
            t.x = v[ii][2*k].x;   t.y = v[ii][2*k].y;
            t.z = v[ii][2*k+1].x; t.w = v[ii][2*k+1].y;
            o4[fb + 12 * ii + k] = t;
        }
}

extern "C" void kernel_launch(void* const* d_in, const int* in_sizes, int n_in,
                              void* d_out, int out_size, void* d_ws, size_t ws_size,
                              hipStream_t stream) {
    const float* u0 = (const float*)d_in[0];
    const float* aw = (const float*)d_in[1];
    const float* bw = (const float*)d_in[2];
    float* out = (float*)d_out;

    const int B = in_sizes[0] / CELLS;   // 16384
    pde_heat_kernel<<<B / WPB, TPB, 0, stream>>>(u0, aw, bw, out);
}